// Round 10
// baseline (278.846 us; speedup 1.0000x reference)
//
#include <hip/hip_runtime.h>

#define SLEN 2048
#define NB 2
#define NHQ 32
#define NHK 8
#define DH 128
#define QBLK 128
#define KVBLK 64
#define NT (SLEN / KVBLK)          // 32
#define NQT (SLEN / QBLK)          // 16
#define KTILE_B (KVBLK * DH * 2)   // 16384 B per K tile image
#define VTILE_B (KVBLK * DH)       // 8192 B per V half-tile image (V0 or V1)

typedef float  f32x4  __attribute__((ext_vector_type(4)));
typedef short  bf16x8 __attribute__((ext_vector_type(8)));

__device__ __forceinline__ unsigned short f2bf(float f) {
  union { float f; unsigned int u; } v; v.f = f;
  return (unsigned short)((v.u + 0x7fffu + ((v.u >> 16) & 1u)) >> 16);
}

__device__ __forceinline__ unsigned int cvtpk(float a, float b) {
  unsigned int r;
  asm("v_cvt_pk_bf16_f32 %0, %1, %2" : "=v"(r) : "v"(a), "v"(b));
  return r;
}

// async global->LDS, 16B per lane. LDS dest is wave-uniform; HW adds lane*16.
#define GLOAD16(g, l)                                                                   \
  __builtin_amdgcn_global_load_lds(                                                    \
      (const __attribute__((address_space(1))) unsigned int*)(g),                      \
      (__attribute__((address_space(3))) unsigned int*)(l), 16, 0, 0)

// ---------------- prep: fp32 K/V -> bf16 tile images in ws --------------------------
// K image : [kv=64 rows of 256B], byte p in row holds K[kv][(p^((kv&7)<<4))/2..]
// V0 image: [d=128 rows of 64B]; logical chunk j (slots 8j..8j+7, kv-half 0) stored at
//           phys chunk j^(d&3); slot s holds V[kvperm(s)][d].
// V1 image: [d=128 rows of 64B] linear; chunk j holds slots 32+8j..+7 (kv-half 1).
// kvperm(p) = (p&32)|((p&4)<<2)|((p&24)>>1)|(p&3): QK^T output regs ARE the PV B-frag.
__global__ __launch_bounds__(256)
void prep_kv(const float* __restrict__ K, const float* __restrict__ V,
             unsigned short* __restrict__ KW, unsigned short* __restrict__ V0W,
             unsigned short* __restrict__ V1W) {
  const int tile = blockIdx.x;
  const int bh   = blockIdx.y;          // b*NHK + kh
  const int tid  = threadIdx.x;
  const size_t krs = (size_t)NB * NHK * DH;
  const float* kb = K + (size_t)bh * DH + (size_t)tile * KVBLK * krs;
  const float* vb = V + (size_t)bh * DH + (size_t)tile * KVBLK * krs;
  unsigned short* kd  = KW  + ((size_t)bh * NT + tile) * (KVBLK * DH);
  unsigned short* v0d = V0W + ((size_t)bh * NT + tile) * (KVBLK * DH / 2);
  unsigned short* v1d = V1W + ((size_t)bh * NT + tile) * (KVBLK * DH / 2);
#pragma unroll
  for (int i = 0; i < 4; ++i) {
    const int cid  = tid + 256 * i;
    const int row  = cid >> 4;                 // kv row
    const int cpos = (cid & 15) << 4;          // dst byte pos
    const int cb   = cpos ^ ((row & 7) << 4);  // src byte col
    const float* s = kb + (size_t)row * krs + (cb >> 1);
    float4 f0 = *(const float4*)s;
    float4 f1 = *(const float4*)(s + 4);
    bf16x8 a;
    a[0]=(short)f2bf(f0.x); a[1]=(short)f2bf(f0.y); a[2]=(short)f2bf(f0.z); a[3]=(short)f2bf(f0.w);
    a[4]=(short)f2bf(f1.x); a[5]=(short)f2bf(f1.y); a[6]=(short)f2bf(f1.z); a[7]=(short)f2bf(f1.w);
    *(bf16x8*)((char*)kd + row * 256 + cpos) = a;
  }
#pragma unroll
  for (int i = 0; i < 4; ++i) {
    const int cid = tid + 256 * i;             // 0..1023
    const int d   = cid >> 3;                  // 0..127
    const int ch  = cid & 7;                   // 0..3 -> V0, 4..7 -> V1
    bf16x8 a;
    if (ch < 4) {
#pragma unroll
      for (int jj = 0; jj < 8; ++jj) {
        const int s2 = 8 * ch + jj;            // logical slot 0..31
        const int kv = ((s2 & 4) << 2) | ((s2 & 24) >> 1) | (s2 & 3);
        a[jj] = (short)f2bf(vb[(size_t)kv * krs + d]);
      }
      *(bf16x8*)((char*)v0d + d * 64 + ((ch ^ (d & 3)) << 4)) = a;
    } else {
      const int j = ch - 4;
#pragma unroll
      for (int jj = 0; jj < 8; ++jj) {
        const int s2 = 8 * j + jj;             // logical slot (within half 1)
        const int kv = 32 | (((s2 & 4) << 2) | ((s2 & 24) >> 1) | (s2 & 3));
        a[jj] = (short)f2bf(vb[(size_t)kv * krs + d]);
      }
      *(bf16x8*)((char*)v1d + d * 64 + (j << 4)) = a;
    }
  }
}

// -------- main: 4 waves x 32 q-rows, static-max softmax, K+V0 LDS-prefetch 1 ahead,
//          V1 per-lane from global (registers), 2 barriers + counted vmcnt ----------
__global__ __launch_bounds__(256, 3)
void fattn_fwd(const float* __restrict__ Q, const unsigned short* __restrict__ KW,
               const unsigned short* __restrict__ V0W, const unsigned short* __restrict__ V1W,
               float* __restrict__ O) {
  const int tid  = threadIdx.x;
  const int w    = tid >> 6;        // wave 0..3
  const int lane = tid & 63;
  const int l15  = lane & 15;
  const int g    = lane >> 4;       // 16-lane group 0..3

  // XCD-chunked swizzle over 1024 blocks: XCD x -> bh in [8x,8x+8), qt descending
  const int wg  = (int)blockIdx.x;
  const int xcd = wg & 7;
  const int c0  = wg >> 3;                  // 0..127
  const int bh  = 8 * xcd + (c0 & 7);       // 0..63
  const int qt  = (NQT - 1) - (c0 >> 3);    // heavy tiles first
  const int b   = bh >> 5;
  const int h   = bh & (NHQ - 1);
  const int kh  = h >> 2;

  __shared__ alignas(16) unsigned short Kbuf[2][KVBLK * DH];        // 2x16KB
  __shared__ alignas(16) unsigned short V0buf[2][DH * (KVBLK / 2)]; // 2x8KB

  const char* kws  = (const char*)(KW  + ((size_t)(b * NHK + kh) * NT) * (KVBLK * DH));
  const char* v0ws = (const char*)(V0W + ((size_t)(b * NHK + kh) * NT) * (KVBLK * DH / 2));
  const char* v1ws = (const char*)(V1W + ((size_t)(b * NHK + kh) * NT) * (KVBLK * DH / 2));

  const float sc = 0.08838834764831845f * 1.4426950408889634f;  // 1/sqrt(128)*log2(e)

  const int qs0 = qt * QBLK + 32 * w;   // wave's first q row (2 strips of 16)
  const int nt  = 2 * qt + 2;

  // ---- Q fragments: fp32 -> (scaled) bf16 in reg ----
  bf16x8 qa[2][4];
#pragma unroll
  for (int u = 0; u < 2; ++u) {
    const float* qp = Q + ((size_t)((qs0 + 16 * u + l15) * NB + b) * NHQ + h) * DH;
#pragma unroll
    for (int s = 0; s < 4; ++s) {
      const float* p = qp + 32 * s + 8 * g;
      float4 f0 = *(const float4*)(p);
      float4 f1 = *(const float4*)(p + 4);
      bf16x8 a;
      a[0]=(short)f2bf(f0.x*sc); a[1]=(short)f2bf(f0.y*sc);
      a[2]=(short)f2bf(f0.z*sc); a[3]=(short)f2bf(f0.w*sc);
      a[4]=(short)f2bf(f1.x*sc); a[5]=(short)f2bf(f1.y*sc);
      a[6]=(short)f2bf(f1.z*sc); a[7]=(short)f2bf(f1.w*sc);
      qa[u][s] = a;
    }
  }

  // ones A-fragment for the lsum MFMA
  bf16x8 ones;
#pragma unroll
  for (int i = 0; i < 8; ++i) ones[i] = (short)0x3F80;

  f32x4 o[2][8];
#pragma unroll
  for (int u = 0; u < 2; ++u)
#pragma unroll
    for (int dt = 0; dt < 8; ++dt) o[u][dt] = (f32x4){0.f, 0.f, 0.f, 0.f};
  f32x4 lacc[2] = {(f32x4){0.f,0.f,0.f,0.f}, (f32x4){0.f,0.f,0.f,0.f}};

  // ---- prologue: stage K[0], V0[0] (6 gloads outstanding entering the loop) ----
#pragma unroll
  for (int i = 0; i < 4; ++i) {
    const int off = i * 4096 + w * 1024;
    GLOAD16(kws + off + (lane << 4), (char*)Kbuf[0] + off);
  }
#pragma unroll
  for (int i = 0; i < 2; ++i) {
    const int off = i * 4096 + w * 1024;
    GLOAD16(v0ws + off + (lane << 4), (char*)V0buf[0] + off);
  }

  int cur = 0;
  for (int it = 0; it < nt; ++it) {
    // ---- Y = V-ks1 half, per-lane global -> regs (consumed ~900cyc later) ----
    const char* yb = v1ws + (size_t)it * VTILE_B + (l15 * 64 + 16 * g);
    bf16x8 Y[8];
#pragma unroll
    for (int dt = 0; dt < 8; ++dt) Y[dt] = *(const bf16x8*)(yb + 1024 * dt);

    // ---- prefetch K[it+1], V0[it+1] one iteration ahead (clamped at tail) ----
    const int pf = (it + 1 < nt) ? it + 1 : it;
    {
      const char* ks = kws + (size_t)pf * KTILE_B;
      const char* vs = v0ws + (size_t)pf * VTILE_B;
#pragma unroll
      for (int i = 0; i < 4; ++i) {
        const int off = i * 4096 + w * 1024;
        GLOAD16(ks + off + (lane << 4), (char*)Kbuf[cur ^ 1] + off);
      }
#pragma unroll
      for (int i = 0; i < 2; ++i) {
        const int off = i * 4096 + w * 1024;
        GLOAD16(vs + off + (lane << 4), (char*)V0buf[cur ^ 1] + off);
      }
    }
    // outstanding: {K[it],V0[it]}(6 oldest) + Y(8) + {K,V0}[it+1](6) -> drain oldest 6
    asm volatile("s_waitcnt vmcnt(14)" ::: "memory");
    __builtin_amdgcn_s_barrier();   // barrier1: K[it], V0[it] visible to all waves
    asm volatile("" ::: "memory");

    const unsigned short* Kc = Kbuf[cur];
    const int kv0 = it * KVBLK;
    const bool live = (kv0 <= qs0 + 31);

    bf16x8 pav[2][2];
    if (live) {
      // ---- swapped QK^T: both strips share each K fragment ----
      f32x4 acc[2][4];
#pragma unroll
      for (int u = 0; u < 2; ++u)
#pragma unroll
        for (int c = 0; c < 4; ++c) acc[u][c] = (f32x4){0.f, 0.f, 0.f, 0.f};
      __builtin_amdgcn_s_setprio(1);
#pragma unroll
      for (int s = 0; s < 4; ++s) {
        const int cb = 64 * s + 16 * g;
#pragma unroll
        for (int c = 0; c < 4; ++c) {
          const int row = 16 * c + l15;
          bf16x8 kfr = *(const bf16x8*)((const char*)Kc + row * 256 + (cb ^ ((row & 7) << 4)));
          acc[0][c] = __builtin_amdgcn_mfma_f32_16x16x32_bf16(kfr, qa[0][s], acc[0][c], 0, 0, 0);
          acc[1][c] = __builtin_amdgcn_mfma_f32_16x16x32_bf16(kfr, qa[1][s], acc[1][c], 0, 0, 0);
        }
      }
      __builtin_amdgcn_s_setprio(0);

      // ---- static-max softmax: P = exp2(s) (masked -> 0), pack to B-fragment ----
#pragma unroll
      for (int u = 0; u < 2; ++u) {
        const int qs   = qs0 + 16 * u;
        const int qrow = qs + l15;
        const bool domask = (kv0 + KVBLK - 1 > qs);
        float p[4][4];
#pragma unroll
        for (int c = 0; c < 4; ++c)
#pragma unroll
          for (int r = 0; r < 4; ++r) {
            float v = acc[u][c][r];
            if (domask) {
              const int kv = kv0 + 16 * c + 4 * g + r;
              v = (kv > qrow) ? -1e30f : v;
            }
            p[c][r] = exp2f(v);
          }
#pragma unroll
        for (int ks = 0; ks < 2; ++ks) {
          union { unsigned int u32[4]; bf16x8 v; } pu;
          pu.u32[0] = cvtpk(p[2 * ks][0], p[2 * ks][1]);
          pu.u32[1] = cvtpk(p[2 * ks][2], p[2 * ks][3]);
          pu.u32[2] = cvtpk(p[2 * ks + 1][0], p[2 * ks + 1][1]);
          pu.u32[3] = cvtpk(p[2 * ks + 1][2], p[2 * ks + 1][3]);
          pav[u][ks] = pu.v;
        }
      }

      // ---- lsum via MFMA ones-column ----
      lacc[0] = __builtin_amdgcn_mfma_f32_16x16x32_bf16(ones, pav[0][0], lacc[0], 0, 0, 0);
      lacc[0] = __builtin_amdgcn_mfma_f32_16x16x32_bf16(ones, pav[0][1], lacc[0], 0, 0, 0);
      lacc[1] = __builtin_amdgcn_mfma_f32_16x16x32_bf16(ones, pav[1][0], lacc[1], 0, 0, 0);
      lacc[1] = __builtin_amdgcn_mfma_f32_16x16x32_bf16(ones, pav[1][1], lacc[1], 0, 0, 0);

      // ---- PV ks=0 from V0buf[cur] (LDS, resident since last iter) ----
      __builtin_amdgcn_s_setprio(1);
#pragma unroll
      for (int dt = 0; dt < 8; ++dt) {
        const int d = 16 * dt + l15;
        bf16x8 vfr = *(const bf16x8*)((const char*)V0buf[cur] + d * 64 +
                                      ((g ^ (d & 3)) << 4));
        o[0][dt] = __builtin_amdgcn_mfma_f32_16x16x32_bf16(vfr, pav[0][0], o[0][dt], 0, 0, 0);
        o[1][dt] = __builtin_amdgcn_mfma_f32_16x16x32_bf16(vfr, pav[1][0], o[1][dt], 0, 0, 0);
      }
      __builtin_amdgcn_s_setprio(0);
    }

    // ---- drain Y (leaves {K,V0}[it+1] in flight), then PV ks=1 from registers ----
    asm volatile("s_waitcnt vmcnt(6)" ::: "memory");
    if (live) {
      __builtin_amdgcn_s_setprio(1);
#pragma unroll
      for (int dt = 0; dt < 8; ++dt) {
        o[0][dt] = __builtin_amdgcn_mfma_f32_16x16x32_bf16(Y[dt], pav[0][1], o[0][dt], 0, 0, 0);
        o[1][dt] = __builtin_amdgcn_mfma_f32_16x16x32_bf16(Y[dt], pav[1][1], o[1][dt], 0, 0, 0);
      }
      __builtin_amdgcn_s_setprio(0);
    }

    asm volatile("" ::: "memory");
    __builtin_amdgcn_s_barrier();   // barrier2: this iter's LDS reads done before
    cur ^= 1;                       //           next iter's gloads overwrite [cur]
  }

  asm volatile("s_waitcnt vmcnt(0)" ::: "memory");  // no pending gload_lds at endpgm

  // ---- epilogue: normalize, store fp32 [s, b, h*d] ----
#pragma unroll
  for (int u = 0; u < 2; ++u) {
    const float rl = 1.0f / lacc[u][0];
    const int qrow = qs0 + 16 * u + l15;
    float* ob = O + ((size_t)b * NHQ + h) * DH + (size_t)qrow * (NB * NHQ * DH);
#pragma unroll
    for (int dt = 0; dt < 8; ++dt) {
      float4 st;
      st.x = o[u][dt][0] * rl; st.y = o[u][dt][1] * rl;
      st.z = o[u][dt][2] * rl; st.w = o[u][dt][3] * rl;
      *(float4*)(ob + 16 * dt + 4 * g) = st;
    }
  }
}

extern "C" void kernel_launch(void* const* d_in, const int* in_sizes, int n_in,
                              void* d_out, int out_size, void* d_ws, size_t ws_size,
                              hipStream_t stream) {
  const float* Q = (const float*)d_in[0];
  const float* K = (const float*)d_in[1];
  const float* V = (const float*)d_in[2];
  float* Out = (float*)d_out;
  unsigned short* W = (unsigned short*)d_ws;   // needs 16.78 MB

  unsigned short* KW  = W;
  unsigned short* V0W = KW + (size_t)NB * NHK * NT * (KVBLK * DH);        // +4.19M shorts
  unsigned short* V1W = V0W + (size_t)NB * NHK * NT * (KVBLK * DH / 2);   // +2.10M shorts

  dim3 pgrid(NT, NB * NHK);
  prep_kv<<<pgrid, 256, 0, stream>>>(K, V, KW, V0W, V1W);

  fattn_fwd<<<dim3(NQT * NB * NHQ), 256, 0, stream>>>(Q, KW, V0W, V1W, Out);
}